// Round 16
// baseline (599.001 us; speedup 1.0000x reference)
//
#include <hip/hip_runtime.h>
#include <math.h>

#define IMG_H 2048
#define IMG_W 2048
#define TILE_X 64
#define TILE_Y 32
#define NBX   (IMG_W / TILE_X)   // 32
#define NBY   (IMG_H / TILE_Y)   // 64
#define STR   72   // LDS row stride in floats (288 B, 16B-aligned)

// NUMERICS ARE LOAD-BEARING (V2 fail 4.69; V5 fail 2.52; V3/V6/V7 pass with
// absmax EXACTLY 0.03125): np reference = V1's exact fp64 expression trees
// in exact evaluation order; magnitude = (float)sqrt((double)m2). Pitfalls:
//   1. fp64 tap-sum reassociation (separable forms) -> NMS tie flips (V2).
//   2. __fsqrt_rn(m2) NOT bit-identical to (float)sqrt((double)m2) here (V5).
// (fma contraction of the chains is bit-safe: all products are powers of two
//  -> exact -> fma's single rounding == add's rounding. V3/V6/V7 verified.)
// V7 measured: 266 us, VALU 61.9%, occ 53.4%, conflicts 3.185e7, VGPR 36.
// V8 (this): pure data-movement. VALU is the binding pipe; converts scale
//   with LDS row-loads (8 cvt/LD8, CSE'd per value). Taller strips cut
//   row-read redundancy; job counts <=128 let waves 2-3 exec-0-skip stages
//   2-3 entirely (V7's wave 3 issued full strips for 12 lanes).
//   Stage 2: 6-row strips, 102 jobs, 2 waves: LD8A issues 20->16.
//   Stage 3: 5-row strips (last=4), 119 jobs, 2 waves: LD8S 18->14,
//   SROW stays 10 (optimal). Stages 1/4 and ALL value macros unchanged.
// CANARY: pass must show absmax EXACTLY 0.03125; anything else = bug.
//
// Coordinate map (per block): buf_a col k <-> global col xa+k, xa=bx*64-4
//   input rows 0..37 <-> global ya+r, ya = by*32-3
//   smoothed buf_s[sr][sc] <-> (ya+1+sr, xa+sc+2), sr=0..35, sc=0..67
//   edges   buf_a[er][ec] <-> (ya+2+er, xa+ec+3), er=0..33, ec=0..65 valid
//   output  (by*32+orow, bx*64+oc), orow=0..31, oc=0..63
// Edge cols 66,67 garbage (uninit buf_s 68,69), never read by NMS (max
// e-col 65). Out-of-image edge values never read (border passthrough).

#define LD8A(DST, ROW, C0) do { \
    *(float4*)&DST[0] = *(const float4*)&buf_a[(ROW) * STR + (C0)]; \
    *(float4*)&DST[4] = *(const float4*)&buf_a[(ROW) * STR + (C0) + 4]; \
} while (0)

#define LD8S(DST, ROW, C0) do { \
    *(float4*)&DST[0] = *(const float4*)&buf_s[(ROW) * STR + (C0)]; \
    *(float4*)&DST[4] = *(const float4*)&buf_s[(ROW) * STR + (C0) + 4]; \
} while (0)

// Gaussian row: EXACT V6 tree (left-assoc chain, same tap order/weights).
#define GROW(RT, RM, RB, SR_) do { \
    float vf[4] __attribute__((aligned(16))); \
    _Pragma("unroll") \
    for (int j = 0; j < 4; ++j) { \
        double v = 0.0625 * (double)RT[j + 1] \
                 + 0.125  * (double)RT[j + 2] \
                 + 0.0625 * (double)RT[j + 3] \
                 + 0.125  * (double)RM[j + 1] \
                 + 0.25   * (double)RM[j + 2] \
                 + 0.125  * (double)RM[j + 3] \
                 + 0.0625 * (double)RB[j + 1] \
                 + 0.125  * (double)RB[j + 2] \
                 + 0.0625 * (double)RB[j + 3]; \
        vf[j] = (float)v; \
    } \
    if (!interior) { \
        int gy = ya + 1 + (SR_); \
        int gx0 = xa + 2 + sc0; \
        bool rowok = (unsigned)gy < IMG_H; \
        _Pragma("unroll") \
        for (int j = 0; j < 4; ++j) \
            if (!(rowok && (unsigned)(gx0 + j) < IMG_W)) vf[j] = 0.f; \
    } \
    *(float4*)&buf_s[(SR_) * STR + sc0] = *(const float4*)vf; \
} while (0)

// Sobel row: EXACT V6 expressions + fp64 sqrt path (PITFALL: keep verbatim).
#define SROW(RT, RM, RB, ER_) do { \
    float vf[4] __attribute__((aligned(16))); \
    _Pragma("unroll") \
    for (int j = 0; j < 4; ++j) { \
        double a = (double)RT[j],  b = (double)RT[j + 1], d = (double)RT[j + 2]; \
        double e = (double)RM[j],                         f = (double)RM[j + 2]; \
        double gg = (double)RB[j], h = (double)RB[j + 1], p = (double)RB[j + 2]; \
        double gxd = (d - a) + 2.0 * (f - e) + (p - gg); \
        double gyd = (gg - a) + 2.0 * (h - b) + (p - d); \
        float gxf = (float)gxd; \
        float gyf = (float)gyd; \
        float m2 = __fadd_rn(__fmul_rn(gxf, gxf), __fmul_rn(gyf, gyf)); \
        vf[j] = (float)sqrt((double)m2); \
    } \
    *(float4*)&buf_a[(ER_) * STR + ec0] = *(const float4*)vf; \
} while (0)

// NMS row: EXACT V6 compare + border passthrough + global float4 store.
#define NMSROW(RT, RM, RB, OROW_) do { \
    float vf[4] __attribute__((aligned(16))); \
    _Pragma("unroll") \
    for (int j = 0; j < 4; ++j) { \
        float cen = RM[j + 1]; \
        float m = fmaxf(fmaxf(fmaxf(RT[j], RT[j + 1]), fmaxf(RT[j + 2], RM[j])), \
                        fmaxf(fmaxf(RM[j + 2], RB[j]), fmaxf(RB[j + 1], RB[j + 2]))); \
        vf[j] = (cen < m) ? 0.f : cen; \
    } \
    int gy = by * TILE_Y + (OROW_); \
    int gx0 = bx * TILE_X + oc0; \
    if (!interior) { \
        bool rowborder = (gy == 0) | (gy == IMG_H - 1); \
        _Pragma("unroll") \
        for (int j = 0; j < 4; ++j) { \
            int gx = gx0 + j; \
            if (rowborder | (gx == 0) | (gx == IMG_W - 1)) vf[j] = RM[j + 1]; \
        } \
    } \
    *reinterpret_cast<float4*>(&outN[(size_t)gy * IMG_W + gx0]) = *(const float4*)vf; \
} while (0)

__global__ __launch_bounds__(256, 7) void edge_kernel(const float* __restrict__ img,
                                                      float* __restrict__ out) {
    __shared__ float buf_a[38 * STR];  // input tile; later reused for edges
    __shared__ float buf_s[36 * STR];  // smoothed tile

    const int tid = threadIdx.x;
    const int bx = blockIdx.x, by = blockIdx.y, n = blockIdx.z;
    const int xa = bx * TILE_X - 4;
    const int ya = by * TILE_Y - 3;
    const float* __restrict__ imgN = img + (size_t)n * (IMG_H * IMG_W);
    float* __restrict__ outN = out + (size_t)n * (IMG_H * IMG_W);
    const bool interior = (bx > 0) & (bx < NBX - 1) & (by > 0) & (by < NBY - 1);

    // ---- stage 1: load 38 rows x 72 cols into buf_a (zero outside) — V6 ----
    if (bx > 0 && bx < NBX - 1) {
        for (int g = tid; g < 38 * 18; g += 256) {
            int r = g / 18, c = g - r * 18;
            int gy = ya + r;
            float4 v = make_float4(0.f, 0.f, 0.f, 0.f);
            if ((unsigned)gy < IMG_H)
                v = *reinterpret_cast<const float4*>(&imgN[(size_t)gy * IMG_W + (xa + 4 * c)]);
            *reinterpret_cast<float4*>(&buf_a[r * STR + 4 * c]) = v;
        }
    } else {
        for (int g = tid; g < 38 * 72; g += 256) {
            int r = g / 72, k = g - r * 72;
            int gy = ya + r, gx = xa + k;
            float v = 0.f;
            if ((unsigned)gy < IMG_H && (unsigned)gx < IMG_W)
                v = imgN[(size_t)gy * IMG_W + gx];
            buf_a[r * STR + k] = v;
        }
    }
    __syncthreads();

    // ---- stage 2: Gaussian, 6 strips(6 rows) x 17 cg = 102 jobs (2 waves;
    //      waves 2-3 exec-0 skip). Sliding 3-row register window. ----------
    if (tid < 102) {
        int s = tid / 17;
        int cg = tid - s * 17;
        int sc0 = 4 * cg;
        int r6 = s * 6;                 // smoothed rows r6..r6+5; input rows r6..r6+7
        float rA[8] __attribute__((aligned(16)));
        float rB[8] __attribute__((aligned(16)));
        float rC[8] __attribute__((aligned(16)));
        LD8A(rA, r6, sc0);
        LD8A(rB, r6 + 1, sc0);
        LD8A(rC, r6 + 2, sc0);  GROW(rA, rB, rC, r6 + 0);
        LD8A(rA, r6 + 3, sc0);  GROW(rB, rC, rA, r6 + 1);
        LD8A(rB, r6 + 4, sc0);  GROW(rC, rA, rB, r6 + 2);
        LD8A(rC, r6 + 5, sc0);  GROW(rA, rB, rC, r6 + 3);
        LD8A(rA, r6 + 6, sc0);  GROW(rB, rC, rA, r6 + 4);
        LD8A(rB, r6 + 7, sc0);  GROW(rC, rA, rB, r6 + 5);
    }
    __syncthreads();

    // ---- stage 3: Sobel, 7 strips (6x5 rows + 1x4) x 17 cg = 119 jobs
    //      (2 waves; waves 2-3 exec-0 skip). ------------------------------
    if (tid < 119) {
        int s = tid / 17;
        int cg = tid - s * 17;
        int ec0 = 4 * cg;
        int e5 = s * 5;                 // edge rows e5..e5+4 (s<6) or e5..e5+3 (s==6)
        float rA[8] __attribute__((aligned(16)));
        float rB[8] __attribute__((aligned(16)));
        float rC[8] __attribute__((aligned(16)));
        LD8S(rA, e5, ec0);
        LD8S(rB, e5 + 1, ec0);
        LD8S(rC, e5 + 2, ec0);  SROW(rA, rB, rC, e5 + 0);
        LD8S(rA, e5 + 3, ec0);  SROW(rB, rC, rA, e5 + 1);
        LD8S(rB, e5 + 4, ec0);  SROW(rC, rA, rB, e5 + 2);
        LD8S(rC, e5 + 5, ec0);  SROW(rA, rB, rC, e5 + 3);
        if (s < 6) {
            LD8S(rA, e5 + 6, ec0);  SROW(rB, rC, rA, e5 + 4);
        }
    }
    __syncthreads();

    // ---- stage 4: NMS, 16 strips(2 rows) x 16 cg = 256 threads (optimal) --
    {
        int st = tid >> 4;
        int oc0 = (tid & 15) * 4;
        int e0 = st * 2;                // edge rows e0..e0+3 for outputs 2st,2st+1
        float r0[8] __attribute__((aligned(16)));
        float r1[8] __attribute__((aligned(16)));
        float r2[8] __attribute__((aligned(16)));
        float r3v[8] __attribute__((aligned(16)));
        LD8A(r0, e0, oc0);
        LD8A(r1, e0 + 1, oc0);
        LD8A(r2, e0 + 2, oc0);
        LD8A(r3v, e0 + 3, oc0);
        NMSROW(r0, r1, r2, 2 * st + 0);
        NMSROW(r1, r2, r3v, 2 * st + 1);
    }
}

extern "C" void kernel_launch(void* const* d_in, const int* in_sizes, int n_in,
                              void* d_out, int out_size, void* d_ws, size_t ws_size,
                              hipStream_t stream) {
    const float* img = (const float*)d_in[0];
    float* out = (float*)d_out;
    dim3 grid(NBX, NBY, 16);
    edge_kernel<<<grid, dim3(256), 0, stream>>>(img, out);
}